// Round 1
// baseline (6527.702 us; speedup 1.0000x reference)
//
#include <hip/hip_runtime.h>

using s16x8 = __attribute__((ext_vector_type(8))) short;
using f32x4 = __attribute__((ext_vector_type(4))) float;
typedef unsigned int   u32;
typedef unsigned short u16;

__device__ __forceinline__ u16 f2bf(float f) {
  u32 u = __float_as_uint(f);
  u += 0x7fffu + ((u >> 16) & 1u);   // round-to-nearest-even
  return (u16)(u >> 16);
}
__device__ __forceinline__ float bf2f(u16 s) {
  return __uint_as_float(((u32)s) << 16);
}

// ---------------------------------------------------------------------------
// Pack weights: Wq/Wk/Wv [H][D][HS] -> wqkvT [3072][1024] bf16 (n = w*1024+h*64+e, k=d)
//               W1 [D][4D] -> w1T [4096][1024] bf16 ; W2 [4D][D] -> w2T [1024][4096] bf16
// ---------------------------------------------------------------------------
__global__ __launch_bounds__(256) void pack_weights(
    const float* __restrict__ Wq, const float* __restrict__ Wk, const float* __restrict__ Wv,
    const float* __restrict__ W1, const float* __restrict__ W2,
    u16* __restrict__ wqkvT, u16* __restrict__ w1T, u16* __restrict__ w2T)
{
  const int idx = blockIdx.x * 256 + threadIdx.x;
  if (idx < 3072 * 1024) {
    const int n = idx >> 10, d = idx & 1023;
    const int w = n >> 10, h = (n >> 6) & 15, e = n & 63;
    const float* src = (w == 0) ? Wq : (w == 1) ? Wk : Wv;
    wqkvT[idx] = f2bf(src[((size_t)h * 1024 + d) * 64 + e]);
  } else if (idx < 3072 * 1024 + 4096 * 1024) {
    const int i = idx - 3072 * 1024;
    const int f = i >> 10, d = i & 1023;
    w1T[i] = f2bf(W1[(size_t)d * 4096 + f]);
  } else {
    const int i = idx - (3072 * 1024 + 4096 * 1024);
    const int dd = i >> 12, f = i & 4095;
    w2T[i] = f2bf(W2[(size_t)f * 1024 + dd]);
  }
}

// ---------------------------------------------------------------------------
// LayerNorm: f32 [4096][1024] -> bf16 [4096][1024]. One block per row.
// ---------------------------------------------------------------------------
__global__ __launch_bounds__(256) void ln_kernel(
    const float* __restrict__ x, const float* __restrict__ g,
    const float* __restrict__ be, u16* __restrict__ out)
{
  const int row = blockIdx.x, tid = threadIdx.x;
  const int lane = tid & 63, wave = tid >> 6;
  const float4 v = ((const float4*)(x + (size_t)row * 1024))[tid];
  float s  = v.x + v.y + v.z + v.w;
  float sq = v.x * v.x + v.y * v.y + v.z * v.z + v.w * v.w;
  #pragma unroll
  for (int m = 1; m < 64; m <<= 1) { s += __shfl_xor(s, m); sq += __shfl_xor(sq, m); }
  __shared__ float rs[4], rq[4];
  if (lane == 0) { rs[wave] = s; rq[wave] = sq; }
  __syncthreads();
  s  = rs[0] + rs[1] + rs[2] + rs[3];
  sq = rq[0] + rq[1] + rq[2] + rq[3];
  const float mean = s * (1.0f / 1024.0f);
  const float var  = sq * (1.0f / 1024.0f) - mean * mean;
  const float rstd = rsqrtf(var + 1e-5f);
  const int c = tid * 4;
  const float4 gv = ((const float4*)g)[tid];
  const float4 bv = ((const float4*)be)[tid];
  ushort4 o;
  o.x = f2bf((v.x - mean) * rstd * gv.x + bv.x);
  o.y = f2bf((v.y - mean) * rstd * gv.y + bv.y);
  o.z = f2bf((v.z - mean) * rstd * gv.z + bv.z);
  o.w = f2bf((v.w - mean) * rstd * gv.w + bv.w);
  *(ushort4*)&out[(size_t)row * 1024 + c] = o;
}

// ---------------------------------------------------------------------------
// bf16 MFMA GEMM: C[M][N] = A[M][K] * BT[N][K]^T.  64x64 tile, 4 waves,
// each wave a 32x32 quadrant of 2x2 16x16x32 MFMA fragments.
// MODE 0: QKV epilogue (scatter q scaled by 1/32; kT/vT chunk-transposed)
// MODE 1: +bias, ReLU -> bf16 hid [4096][4096]
// MODE 2: +bias +resid -> f32 out [4096][1024]
// ---------------------------------------------------------------------------
template<int MODE>
__global__ __launch_bounds__(256) void gemm64(
    const u16* __restrict__ A, const u16* __restrict__ BT, int K,
    u16* __restrict__ o0q, u16* __restrict__ o0k, u16* __restrict__ o0v,
    u16* __restrict__ o1, const float* __restrict__ bias,
    float* __restrict__ o2, const float* __restrict__ resid)
{
  __shared__ alignas(16) u16 As[64][40];   // [row][k], padded to 40 (80B rows)
  __shared__ alignas(16) u16 Bs[64][40];   // [col][k]
  const int tid = threadIdx.x;
  const int lane = tid & 63, wave = tid >> 6;
  const int wr = wave >> 1, wc = wave & 1;
  const int row0 = blockIdx.y * 64, col0 = blockIdx.x * 64;
  const int str_r = tid >> 2, str_c = (tid & 3) * 8;  // staging: 16B per thread
  const int fr = lane & 15, ko = (lane >> 4) * 8;     // fragment addressing

  f32x4 acc[2][2] = {};
  const u16* Ap = A + (size_t)(row0 + str_r) * K + str_c;
  const u16* Bp = BT + (size_t)(col0 + str_r) * K + str_c;

  for (int k0 = 0; k0 < K; k0 += 32) {
    __syncthreads();
    *(uint4*)&As[str_r][str_c] = *(const uint4*)(Ap + k0);
    *(uint4*)&Bs[str_r][str_c] = *(const uint4*)(Bp + k0);
    __syncthreads();
    s16x8 a0 = *(const s16x8*)&As[wr * 32 + fr][ko];
    s16x8 a1 = *(const s16x8*)&As[wr * 32 + 16 + fr][ko];
    s16x8 b0 = *(const s16x8*)&Bs[wc * 32 + fr][ko];
    s16x8 b1 = *(const s16x8*)&Bs[wc * 32 + 16 + fr][ko];
    acc[0][0] = __builtin_amdgcn_mfma_f32_16x16x32_bf16(a0, b0, acc[0][0], 0, 0, 0);
    acc[0][1] = __builtin_amdgcn_mfma_f32_16x16x32_bf16(a0, b1, acc[0][1], 0, 0, 0);
    acc[1][0] = __builtin_amdgcn_mfma_f32_16x16x32_bf16(a1, b0, acc[1][0], 0, 0, 0);
    acc[1][1] = __builtin_amdgcn_mfma_f32_16x16x32_bf16(a1, b1, acc[1][1], 0, 0, 0);
  }

  #pragma unroll
  for (int m = 0; m < 2; ++m) {
    const int rbase = row0 + wr * 32 + m * 16 + (lane >> 4) * 4;  // 4 consecutive rows
    #pragma unroll
    for (int n = 0; n < 2; ++n) {
      const int col = col0 + wc * 32 + n * 16 + fr;
      if constexpr (MODE == 0) {
        const int w = col >> 10, h = (col >> 6) & 15, e = col & 63;
        const int b = rbase >> 11, t0 = rbase & 2047;
        const int bh = b * 16 + h;
        if (w == 0) {
          #pragma unroll
          for (int j = 0; j < 4; ++j)
            o0q[((size_t)bh * 2048 + (t0 + j)) * 64 + e] = f2bf(acc[m][n][j] * 0.03125f);
        } else {
          ushort4 pk;
          pk.x = f2bf(acc[m][n][0]); pk.y = f2bf(acc[m][n][1]);
          pk.z = f2bf(acc[m][n][2]); pk.w = f2bf(acc[m][n][3]);
          u16* dst = (w == 1) ? o0k : o0v;
          // layout [bh][sChunk=t0>>6][e][s&63]
          *(ushort4*)&dst[(size_t)(bh * 32 + (t0 >> 6)) * 4096 + e * 64 + (t0 & 63)] = pk;
        }
      } else if constexpr (MODE == 1) {
        const float bb = bias[col];
        #pragma unroll
        for (int j = 0; j < 4; ++j) {
          float v = fmaxf(acc[m][n][j] + bb, 0.0f);
          o1[(size_t)(rbase + j) * 4096 + col] = f2bf(v);
        }
      } else {
        const float bb = bias[col];
        #pragma unroll
        for (int j = 0; j < 4; ++j) {
          const size_t ix = (size_t)(rbase + j) * 1024 + col;
          o2[ix] = acc[m][n][j] + bb + resid[ix];
        }
      }
    }
  }
}

// ---------------------------------------------------------------------------
// Causal attention, online softmax. 1 wave = 1 query row, lane = kv position
// within a 64-wide chunk. q pre-scaled by d^-0.5. K/V in [bh][chunk][e][64].
// Writes embds2 = embds + attn (f32).
// ---------------------------------------------------------------------------
__global__ __launch_bounds__(256) void attn_kernel(
    const u16* __restrict__ q, const u16* __restrict__ kc,
    const u16* __restrict__ vc, const float* __restrict__ embds,
    float* __restrict__ e2)
{
  const int tid = threadIdx.x, lane = tid & 63, wave = tid >> 6;
  const int bid = blockIdx.x;
  const int bh = bid >> 9, tile = bid & 511;
  const int t = tile * 4 + wave;
  const int b = bh >> 4, h = bh & 15;

  __shared__ alignas(16) float q_sm[4][64];
  q_sm[wave][lane] = bf2f(q[((size_t)bh * 2048 + t) * 64 + lane]);
  __syncthreads();

  float o[64];
  #pragma unroll
  for (int e = 0; e < 64; ++e) o[e] = 0.0f;
  float mrun = -1e30f, lrun = 0.0f;

  const float4* qv4 = (const float4*)q_sm[wave];
  const size_t bhbase = (size_t)bh * 32 * 4096;
  const float LOG2E = 1.4426950408889634f;

  for (int s0 = 0; s0 <= t; s0 += 64) {
    const u16* kcp = kc + bhbase + (size_t)(s0 >> 6) * 4096 + lane;
    const u16* vcp = vc + bhbase + (size_t)(s0 >> 6) * 4096 + lane;
    float sc = 0.0f;
    #pragma unroll
    for (int e4 = 0; e4 < 16; ++e4) {
      const float4 qe = qv4[e4];
      sc = fmaf(bf2f(kcp[(e4 * 4 + 0) * 64]), qe.x, sc);
      sc = fmaf(bf2f(kcp[(e4 * 4 + 1) * 64]), qe.y, sc);
      sc = fmaf(bf2f(kcp[(e4 * 4 + 2) * 64]), qe.z, sc);
      sc = fmaf(bf2f(kcp[(e4 * 4 + 3) * 64]), qe.w, sc);
    }
    if (s0 + lane > t) sc = -1e30f;      // causal mask (partial last chunk)
    float cm = sc;
    #pragma unroll
    for (int mm = 1; mm < 64; mm <<= 1) cm = fmaxf(cm, __shfl_xor(cm, mm));
    if (cm > mrun) {                      // wave-uniform: rescale only on max growth
      const float f = __builtin_amdgcn_exp2f((mrun - cm) * LOG2E);
      #pragma unroll
      for (int e = 0; e < 64; ++e) o[e] *= f;
      lrun *= f;
      mrun = cm;
    }
    float p = __builtin_amdgcn_exp2f((sc - mrun) * LOG2E);
    float ps = p;
    #pragma unroll
    for (int mm = 1; mm < 64; mm <<= 1) ps += __shfl_xor(ps, mm);
    lrun += ps;
    #pragma unroll
    for (int e = 0; e < 64; ++e)
      o[e] = fmaf(bf2f(vcp[e * 64]), p, o[e]);
  }

  // cross-lane combine: o_final[lane] = sum_j o_j[lane]
  float of = 0.0f;
  #pragma unroll
  for (int e = 0; e < 64; ++e) {
    float s = o[e];
    #pragma unroll
    for (int mm = 1; mm < 64; mm <<= 1) s += __shfl_xor(s, mm);
    if (lane == e) of = s;
  }
  const size_t oidx = ((size_t)b * 2048 + t) * 1024 + (size_t)h * 64 + lane;
  e2[oidx] = embds[oidx] + of / lrun;
}

// ---------------------------------------------------------------------------
extern "C" void kernel_launch(void* const* d_in, const int* in_sizes, int n_in,
                              void* d_out, int out_size, void* d_ws, size_t ws_size,
                              hipStream_t stream) {
  const float* embds = (const float*)d_in[0];
  const float* Wq    = (const float*)d_in[1];
  const float* Wk    = (const float*)d_in[2];
  const float* Wv    = (const float*)d_in[3];
  const float* ln1g  = (const float*)d_in[4];
  const float* ln1b  = (const float*)d_in[5];
  const float* ln2g  = (const float*)d_in[6];
  const float* ln2b  = (const float*)d_in[7];
  const float* W1    = (const float*)d_in[8];
  const float* b1    = (const float*)d_in[9];
  const float* W2    = (const float*)d_in[10];
  const float* b2    = (const float*)d_in[11];
  float* out = (float*)d_out;

  char* ws = (char*)d_ws;
  u16*   xln   = (u16*)(ws);                          // 8 MB  xln [4096][1024] bf16
  u16*   wqkvT = (u16*)(ws + (8ull  << 20));          // 6 MB  [3072][1024]
  u16*   qbuf  = (u16*)(ws + (14ull << 20));          // 8 MB  [bh][t][64]
  u16*   kTc   = (u16*)(ws + (22ull << 20));          // 8 MB  [bh][chunk][e][64]
  u16*   vTc   = (u16*)(ws + (30ull << 20));          // 8 MB
  float* e2    = (float*)(ws + (38ull << 20));        // 16 MB embds2 f32
  u16*   ybuf  = (u16*)(ws + (54ull << 20));          // 8 MB
  u16*   w1T   = (u16*)(ws + (62ull << 20));          // 8 MB  [4096][1024]
  u16*   w2T   = (u16*)(ws + (70ull << 20));          // 8 MB  [1024][4096]
  u16*   hid   = (u16*)(ws + (78ull << 20));          // 32 MB [4096][4096]  -> 110 MB total

  pack_weights<<<45056, 256, 0, stream>>>(Wq, Wk, Wv, W1, W2, wqkvT, w1T, w2T);
  ln_kernel<<<4096, 256, 0, stream>>>(embds, ln1g, ln1b, xln);
  gemm64<0><<<dim3(48, 64), 256, 0, stream>>>(xln, wqkvT, 1024,
      qbuf, kTc, vTc, nullptr, nullptr, nullptr, nullptr);
  attn_kernel<<<16384, 256, 0, stream>>>(qbuf, kTc, vTc, embds, e2);
  ln_kernel<<<4096, 256, 0, stream>>>(e2, ln2g, ln2b, ybuf);
  gemm64<1><<<dim3(64, 64), 256, 0, stream>>>(ybuf, w1T, 1024,
      nullptr, nullptr, nullptr, hid, b1, nullptr, nullptr);
  gemm64<2><<<dim3(16, 64), 256, 0, stream>>>(hid, w2T, 4096,
      nullptr, nullptr, nullptr, nullptr, b2, out, e2);
}

// Round 2
// 419.000 us; speedup vs baseline: 15.5792x; 15.5792x over previous
//
#include <hip/hip_runtime.h>

using s16x8 = __attribute__((ext_vector_type(8))) short;
using f32x4 = __attribute__((ext_vector_type(4))) float;
typedef unsigned int   u32;
typedef unsigned short u16;

__device__ __forceinline__ u16 f2bf(float f) {
  u32 u = __float_as_uint(f);
  u += 0x7fffu + ((u >> 16) & 1u);   // round-to-nearest-even
  return (u16)(u >> 16);
}
__device__ __forceinline__ float bf2f(u16 s) {
  return __uint_as_float(((u32)s) << 16);
}

// ---------------------------------------------------------------------------
// Pack weights: Wq/Wk/Wv [H][D][HS] -> wqkvT [3072][1024] bf16 (n = w*1024+h*64+e, k=d)
//               W1 [D][4D] -> w1T [4096][1024] bf16 ; W2 [4D][D] -> w2T [1024][4096] bf16
// ---------------------------------------------------------------------------
__global__ __launch_bounds__(256) void pack_weights(
    const float* __restrict__ Wq, const float* __restrict__ Wk, const float* __restrict__ Wv,
    const float* __restrict__ W1, const float* __restrict__ W2,
    u16* __restrict__ wqkvT, u16* __restrict__ w1T, u16* __restrict__ w2T)
{
  const int idx = blockIdx.x * 256 + threadIdx.x;
  if (idx < 3072 * 1024) {
    const int n = idx >> 10, d = idx & 1023;
    const int w = n >> 10, h = (n >> 6) & 15, e = n & 63;
    const float* src = (w == 0) ? Wq : (w == 1) ? Wk : Wv;
    wqkvT[idx] = f2bf(src[((size_t)h * 1024 + d) * 64 + e]);
  } else if (idx < 3072 * 1024 + 4096 * 1024) {
    const int i = idx - 3072 * 1024;
    const int f = i >> 10, d = i & 1023;
    w1T[i] = f2bf(W1[(size_t)d * 4096 + f]);
  } else {
    const int i = idx - (3072 * 1024 + 4096 * 1024);
    const int dd = i >> 12, f = i & 4095;
    w2T[i] = f2bf(W2[(size_t)f * 1024 + dd]);
  }
}

// ---------------------------------------------------------------------------
// LayerNorm: f32 [4096][1024] -> bf16 [4096][1024]. One block per row.
// ---------------------------------------------------------------------------
__global__ __launch_bounds__(256) void ln_kernel(
    const float* __restrict__ x, const float* __restrict__ g,
    const float* __restrict__ be, u16* __restrict__ out)
{
  const int row = blockIdx.x, tid = threadIdx.x;
  const int lane = tid & 63, wave = tid >> 6;
  const float4 v = ((const float4*)(x + (size_t)row * 1024))[tid];
  float s  = v.x + v.y + v.z + v.w;
  float sq = v.x * v.x + v.y * v.y + v.z * v.z + v.w * v.w;
  #pragma unroll
  for (int m = 1; m < 64; m <<= 1) { s += __shfl_xor(s, m); sq += __shfl_xor(sq, m); }
  __shared__ float rs[4], rq[4];
  if (lane == 0) { rs[wave] = s; rq[wave] = sq; }
  __syncthreads();
  s  = rs[0] + rs[1] + rs[2] + rs[3];
  sq = rq[0] + rq[1] + rq[2] + rq[3];
  const float mean = s * (1.0f / 1024.0f);
  const float var  = sq * (1.0f / 1024.0f) - mean * mean;
  const float rstd = rsqrtf(var + 1e-5f);
  const int c = tid * 4;
  const float4 gv = ((const float4*)g)[tid];
  const float4 bv = ((const float4*)be)[tid];
  ushort4 o;
  o.x = f2bf((v.x - mean) * rstd * gv.x + bv.x);
  o.y = f2bf((v.y - mean) * rstd * gv.y + bv.y);
  o.z = f2bf((v.z - mean) * rstd * gv.z + bv.z);
  o.w = f2bf((v.w - mean) * rstd * gv.w + bv.w);
  *(ushort4*)&out[(size_t)row * 1024 + c] = o;
}

// ---------------------------------------------------------------------------
// bf16 MFMA GEMM: C[M][N] = A[M][K] * BT[N][K]^T.  64x64 tile, 4 waves,
// each wave a 32x32 quadrant of 2x2 16x16x32 MFMA fragments.
// MODE 0: QKV epilogue (q scaled 1/32 -> [bh][t][64]; K -> [bh][t][64];
//         V -> transposed [bh][e][t])
// MODE 1: +bias, ReLU -> bf16 hid [4096][4096]
// MODE 2: +bias +resid -> f32 out [4096][1024]
// ---------------------------------------------------------------------------
template<int MODE>
__global__ __launch_bounds__(256) void gemm64(
    const u16* __restrict__ A, const u16* __restrict__ BT, int K,
    u16* __restrict__ o0q, u16* __restrict__ o0k, u16* __restrict__ o0v,
    u16* __restrict__ o1, const float* __restrict__ bias,
    float* __restrict__ o2, const float* __restrict__ resid)
{
  __shared__ alignas(16) u16 As[64][40];   // [row][k], padded to 40 (80B rows)
  __shared__ alignas(16) u16 Bs[64][40];   // [col][k]
  const int tid = threadIdx.x;
  const int lane = tid & 63, wave = tid >> 6;
  const int wr = wave >> 1, wc = wave & 1;
  const int row0 = blockIdx.y * 64, col0 = blockIdx.x * 64;
  const int str_r = tid >> 2, str_c = (tid & 3) * 8;  // staging: 16B per thread
  const int fr = lane & 15, ko = (lane >> 4) * 8;     // fragment addressing

  f32x4 acc[2][2] = {};
  const u16* Ap = A + (size_t)(row0 + str_r) * K + str_c;
  const u16* Bp = BT + (size_t)(col0 + str_r) * K + str_c;

  for (int k0 = 0; k0 < K; k0 += 32) {
    __syncthreads();
    *(uint4*)&As[str_r][str_c] = *(const uint4*)(Ap + k0);
    *(uint4*)&Bs[str_r][str_c] = *(const uint4*)(Bp + k0);
    __syncthreads();
    s16x8 a0 = *(const s16x8*)&As[wr * 32 + fr][ko];
    s16x8 a1 = *(const s16x8*)&As[wr * 32 + 16 + fr][ko];
    s16x8 b0 = *(const s16x8*)&Bs[wc * 32 + fr][ko];
    s16x8 b1 = *(const s16x8*)&Bs[wc * 32 + 16 + fr][ko];
    acc[0][0] = __builtin_amdgcn_mfma_f32_16x16x32_bf16(a0, b0, acc[0][0], 0, 0, 0);
    acc[0][1] = __builtin_amdgcn_mfma_f32_16x16x32_bf16(a0, b1, acc[0][1], 0, 0, 0);
    acc[1][0] = __builtin_amdgcn_mfma_f32_16x16x32_bf16(a1, b0, acc[1][0], 0, 0, 0);
    acc[1][1] = __builtin_amdgcn_mfma_f32_16x16x32_bf16(a1, b1, acc[1][1], 0, 0, 0);
  }

  #pragma unroll
  for (int m = 0; m < 2; ++m) {
    const int rbase = row0 + wr * 32 + m * 16 + (lane >> 4) * 4;  // 4 consecutive rows
    #pragma unroll
    for (int n = 0; n < 2; ++n) {
      const int col = col0 + wc * 32 + n * 16 + fr;
      if constexpr (MODE == 0) {
        const int w = col >> 10, h = (col >> 6) & 15, e = col & 63;
        const int b = rbase >> 11, t0 = rbase & 2047;
        const int bh = b * 16 + h;
        if (w == 0) {
          #pragma unroll
          for (int j = 0; j < 4; ++j)
            o0q[((size_t)bh * 2048 + (t0 + j)) * 64 + e] = f2bf(acc[m][n][j] * 0.03125f);
        } else if (w == 1) {
          #pragma unroll
          for (int j = 0; j < 4; ++j)
            o0k[((size_t)bh * 2048 + (t0 + j)) * 64 + e] = f2bf(acc[m][n][j]);
        } else {
          ushort4 pk;
          pk.x = f2bf(acc[m][n][0]); pk.y = f2bf(acc[m][n][1]);
          pk.z = f2bf(acc[m][n][2]); pk.w = f2bf(acc[m][n][3]);
          // V transposed: [bh][e][t]
          *(ushort4*)&o0v[((size_t)bh * 64 + e) * 2048 + t0] = pk;
        }
      } else if constexpr (MODE == 1) {
        const float bb = bias[col];
        #pragma unroll
        for (int j = 0; j < 4; ++j) {
          float v = fmaxf(acc[m][n][j] + bb, 0.0f);
          o1[(size_t)(rbase + j) * 4096 + col] = f2bf(v);
        }
      } else {
        const float bb = bias[col];
        #pragma unroll
        for (int j = 0; j < 4; ++j) {
          const size_t ix = (size_t)(rbase + j) * 1024 + col;
          o2[ix] = acc[m][n][j] + bb + resid[ix];
        }
      }
    }
  }
}

// ---------------------------------------------------------------------------
// MFMA flash attention. 1 wave = 1 (bh, 16-row q-tile); 4 independent waves
// per block (no barriers). KV chunk = 64. q pre-scaled by d^-0.5.
// K row-major [bh][t][64]; V transposed [bh][e][t].
// Fragment conventions identical to gemm64 (verified):
//   A-frag: row=lane&15, k=(lane>>4)*8+0..7 ; B-frag: col=lane&15, same k
//   C/D:    col=lane&15, row=(lane>>4)*4+j
// ---------------------------------------------------------------------------
__global__ __launch_bounds__(256) void attn_mfma(
    const u16* __restrict__ q, const u16* __restrict__ krow,
    const u16* __restrict__ vT, const float* __restrict__ embds,
    float* __restrict__ e2)
{
  __shared__ alignas(16) u16 p_sm[4][16][72];   // per-wave P buffer, 144B rows
  const int tid = threadIdx.x, lane = tid & 63, wave = tid >> 6;
  const int task = blockIdx.x * 4 + wave;       // 4096 tasks
  const int bh = task & 31;
  const int qt = 127 - (task >> 5);             // long q-tiles scheduled first
  const int q0 = qt * 16;
  const int b = bh >> 4, h = bh & 15;
  const int fr = lane & 15, g = lane >> 4;

  // Q fragments (2 k-steps of 32 over head dim 64)
  const u16* qp = q + ((size_t)bh * 2048 + q0 + fr) * 64 + g * 8;
  const s16x8 qf0 = *(const s16x8*)(qp);
  const s16x8 qf1 = *(const s16x8*)(qp + 32);

  f32x4 o_acc[4] = {};                          // 4 e-tiles x 4 q-rows
  float m_j[4], l_j[4];
  #pragma unroll
  for (int j = 0; j < 4; ++j) { m_j[j] = -1e30f; l_j[j] = 0.0f; }

  const size_t kvbase = (size_t)bh * 2048 * 64;
  const int nch = ((q0 + 15) >> 6) + 1;
  const float LOG2E = 1.4426950408889634f;

  for (int c = 0; c < nch; ++c) {
    const int s0 = c * 64;

    // ---- QK^T: S[16 q][64 s] ----
    f32x4 sacc[4] = {};
    #pragma unroll
    for (int n = 0; n < 4; ++n) {
      const u16* kp = krow + kvbase + (size_t)(s0 + n * 16 + fr) * 64 + g * 8;
      const s16x8 kf0 = *(const s16x8*)(kp);
      const s16x8 kf1 = *(const s16x8*)(kp + 32);
      sacc[n] = __builtin_amdgcn_mfma_f32_16x16x32_bf16(qf0, kf0, sacc[n], 0, 0, 0);
      sacc[n] = __builtin_amdgcn_mfma_f32_16x16x32_bf16(qf1, kf1, sacc[n], 0, 0, 0);
    }

    // ---- causal mask (only chunk containing the diagonal) ----
    if (s0 + 63 > q0) {
      #pragma unroll
      for (int n = 0; n < 4; ++n) {
        const int s = s0 + n * 16 + fr;
        #pragma unroll
        for (int j = 0; j < 4; ++j) {
          if (s > q0 + g * 4 + j) sacc[n][j] = -1e30f;
        }
      }
    }

    // ---- online softmax (row = q, reduce across 16-lane groups) ----
    float p[4][4];
    f32x4 fvec;
    #pragma unroll
    for (int j = 0; j < 4; ++j) {
      float mx = fmaxf(fmaxf(sacc[0][j], sacc[1][j]), fmaxf(sacc[2][j], sacc[3][j]));
      #pragma unroll
      for (int mm = 1; mm < 16; mm <<= 1) mx = fmaxf(mx, __shfl_xor(mx, mm));
      const float mnew = fmaxf(m_j[j], mx);
      const float f = __builtin_amdgcn_exp2f((m_j[j] - mnew) * LOG2E);
      m_j[j] = mnew;
      float rs = 0.0f;
      #pragma unroll
      for (int n = 0; n < 4; ++n) {
        const float pe = __builtin_amdgcn_exp2f((sacc[n][j] - mnew) * LOG2E);
        p[n][j] = pe; rs += pe;
      }
      #pragma unroll
      for (int mm = 1; mm < 16; mm <<= 1) rs += __shfl_xor(rs, mm);
      l_j[j] = l_j[j] * f + rs;
      fvec[j] = f;
    }
    #pragma unroll
    for (int n = 0; n < 4; ++n) o_acc[n] *= fvec;

    // ---- P -> LDS (transpose to A-fragment layout); single wave, in-order DS ----
    #pragma unroll
    for (int n = 0; n < 4; ++n)
      #pragma unroll
      for (int j = 0; j < 4; ++j)
        p_sm[wave][g * 4 + j][n * 16 + fr] = f2bf(p[n][j]);

    const s16x8 pf0 = *(const s16x8*)&p_sm[wave][fr][g * 8];
    const s16x8 pf1 = *(const s16x8*)&p_sm[wave][fr][32 + g * 8];

    // ---- PV: O += P[16 q][64 s] * V[64 s][64 e] ----
    #pragma unroll
    for (int n = 0; n < 4; ++n) {
      const u16* vp = vT + kvbase + (size_t)(n * 16 + fr) * 2048 + s0 + g * 8;
      const s16x8 vf0 = *(const s16x8*)(vp);
      const s16x8 vf1 = *(const s16x8*)(vp + 32);
      o_acc[n] = __builtin_amdgcn_mfma_f32_16x16x32_bf16(pf0, vf0, o_acc[n], 0, 0, 0);
      o_acc[n] = __builtin_amdgcn_mfma_f32_16x16x32_bf16(pf1, vf1, o_acc[n], 0, 0, 0);
    }
  }

  // ---- epilogue: e2 = embds + O/l ----
  #pragma unroll
  for (int n = 0; n < 4; ++n) {
    #pragma unroll
    for (int j = 0; j < 4; ++j) {
      const int t = q0 + g * 4 + j;
      const size_t oi = ((size_t)b * 2048 + t) * 1024 + (size_t)h * 64 + n * 16 + fr;
      e2[oi] = embds[oi] + o_acc[n][j] / l_j[j];
    }
  }
}

// ---------------------------------------------------------------------------
extern "C" void kernel_launch(void* const* d_in, const int* in_sizes, int n_in,
                              void* d_out, int out_size, void* d_ws, size_t ws_size,
                              hipStream_t stream) {
  const float* embds = (const float*)d_in[0];
  const float* Wq    = (const float*)d_in[1];
  const float* Wk    = (const float*)d_in[2];
  const float* Wv    = (const float*)d_in[3];
  const float* ln1g  = (const float*)d_in[4];
  const float* ln1b  = (const float*)d_in[5];
  const float* ln2g  = (const float*)d_in[6];
  const float* ln2b  = (const float*)d_in[7];
  const float* W1    = (const float*)d_in[8];
  const float* b1    = (const float*)d_in[9];
  const float* W2    = (const float*)d_in[10];
  const float* b2    = (const float*)d_in[11];
  float* out = (float*)d_out;

  char* ws = (char*)d_ws;
  u16*   xln   = (u16*)(ws);                          // 8 MB  xln [4096][1024] bf16
  u16*   wqkvT = (u16*)(ws + (8ull  << 20));          // 6 MB  [3072][1024]
  u16*   qbuf  = (u16*)(ws + (14ull << 20));          // 8 MB  [bh][t][64]
  u16*   krow  = (u16*)(ws + (22ull << 20));          // 8 MB  [bh][t][64]
  u16*   vTb   = (u16*)(ws + (30ull << 20));          // 8 MB  [bh][e][t]
  float* e2    = (float*)(ws + (38ull << 20));        // 16 MB embds2 f32
  u16*   ybuf  = (u16*)(ws + (54ull << 20));          // 8 MB
  u16*   w1T   = (u16*)(ws + (62ull << 20));          // 8 MB  [4096][1024]
  u16*   w2T   = (u16*)(ws + (70ull << 20));          // 8 MB  [1024][4096]
  u16*   hid   = (u16*)(ws + (78ull << 20));          // 32 MB [4096][4096]

  pack_weights<<<45056, 256, 0, stream>>>(Wq, Wk, Wv, W1, W2, wqkvT, w1T, w2T);
  ln_kernel<<<4096, 256, 0, stream>>>(embds, ln1g, ln1b, xln);
  gemm64<0><<<dim3(48, 64), 256, 0, stream>>>(xln, wqkvT, 1024,
      qbuf, krow, vTb, nullptr, nullptr, nullptr, nullptr);
  attn_mfma<<<1024, 256, 0, stream>>>(qbuf, krow, vTb, embds, e2);
  ln_kernel<<<4096, 256, 0, stream>>>(e2, ln2g, ln2b, ybuf);
  gemm64<1><<<dim3(64, 64), 256, 0, stream>>>(ybuf, w1T, 1024,
      nullptr, nullptr, nullptr, hid, b1, nullptr, nullptr);
  gemm64<2><<<dim3(16, 64), 256, 0, stream>>>(hid, w2T, 4096,
      nullptr, nullptr, nullptr, nullptr, b2, out, e2);
}

// Round 3
// 361.634 us; speedup vs baseline: 18.0506x; 1.1586x over previous
//
#include <hip/hip_runtime.h>

using s16x8 = __attribute__((ext_vector_type(8))) short;
using f32x4 = __attribute__((ext_vector_type(4))) float;
typedef unsigned int   u32;
typedef unsigned short u16;

__device__ __forceinline__ u16 f2bf(float f) {
  u32 u = __float_as_uint(f);
  u += 0x7fffu + ((u >> 16) & 1u);   // round-to-nearest-even
  return (u16)(u >> 16);
}
__device__ __forceinline__ float bf2f(u16 s) {
  return __uint_as_float(((u32)s) << 16);
}

typedef __attribute__((address_space(1))) const unsigned int g_u32;
typedef __attribute__((address_space(3))) unsigned int l_u32;
__device__ __forceinline__ void gload16(const void* g, void* l) {
  __builtin_amdgcn_global_load_lds((g_u32*)g, (l_u32*)l, 16, 0, 0);
}

// ---------------------------------------------------------------------------
// Tiled transpose+pack: src f32 [z][R][C] -> dst bf16 [z][C][R]. 64x64 tiles.
// ---------------------------------------------------------------------------
__global__ __launch_bounds__(256) void transpose_pack(
    const float* __restrict__ src, u16* __restrict__ dst, int R, int C)
{
  __shared__ u16 tile[64][66];
  const int tid = threadIdx.x;
  const int c0 = blockIdx.x * 64, r0 = blockIdx.y * 64;
  const size_t zoff = (size_t)blockIdx.z * R * C;
  src += zoff; dst += zoff;
  const int rr = tid >> 6, cc = tid & 63;
  #pragma unroll
  for (int i = 0; i < 16; ++i)
    tile[i * 4 + rr][cc] = f2bf(src[(size_t)(r0 + i * 4 + rr) * C + c0 + cc]);
  __syncthreads();
  #pragma unroll
  for (int i = 0; i < 16; ++i)
    dst[(size_t)(c0 + i * 4 + rr) * R + r0 + cc] = tile[cc][i * 4 + rr];
}

// ---------------------------------------------------------------------------
// LayerNorm: f32 [4096][1024] -> bf16 [4096][1024]. One block per row.
// ---------------------------------------------------------------------------
__global__ __launch_bounds__(256) void ln_kernel(
    const float* __restrict__ x, const float* __restrict__ g,
    const float* __restrict__ be, u16* __restrict__ out)
{
  const int row = blockIdx.x, tid = threadIdx.x;
  const int lane = tid & 63, wave = tid >> 6;
  const float4 v = ((const float4*)(x + (size_t)row * 1024))[tid];
  float s  = v.x + v.y + v.z + v.w;
  float sq = v.x * v.x + v.y * v.y + v.z * v.z + v.w * v.w;
  #pragma unroll
  for (int m = 1; m < 64; m <<= 1) { s += __shfl_xor(s, m); sq += __shfl_xor(sq, m); }
  __shared__ float rs[4], rq[4];
  if (lane == 0) { rs[wave] = s; rq[wave] = sq; }
  __syncthreads();
  s  = rs[0] + rs[1] + rs[2] + rs[3];
  sq = rq[0] + rq[1] + rq[2] + rq[3];
  const float mean = s * (1.0f / 1024.0f);
  const float var  = sq * (1.0f / 1024.0f) - mean * mean;
  const float rstd = rsqrtf(var + 1e-5f);
  const int c = tid * 4;
  const float4 gv = ((const float4*)g)[tid];
  const float4 bv = ((const float4*)be)[tid];
  ushort4 o;
  o.x = f2bf((v.x - mean) * rstd * gv.x + bv.x);
  o.y = f2bf((v.y - mean) * rstd * gv.y + bv.y);
  o.z = f2bf((v.z - mean) * rstd * gv.z + bv.z);
  o.w = f2bf((v.w - mean) * rstd * gv.w + bv.w);
  *(ushort4*)&out[(size_t)row * 1024 + c] = o;
}

// ---------------------------------------------------------------------------
// m97-structure bf16 GEMM: C[M][N] = A[M][K]*BT[N][K]^T. 128x128 tile, BK=32,
// 4 waves (2x2 of 64x64), 4x4 16x16x32 fragments/wave, global_load_lds(16B).
// MODE 0: QKV epilogue (q scaled by LOG2E/32 -> [bh][t][64]; K -> [bh][t][64];
//         V -> transposed [bh][e][t])
// MODE 1: +bias, ReLU -> bf16 hid [4096][4096]
// MODE 2: +bias +resid -> f32 out [4096][1024]
// ---------------------------------------------------------------------------
template<int MODE>
__global__ __launch_bounds__(256) void gemm128(
    const u16* __restrict__ A, const u16* __restrict__ BT, int K,
    u16* __restrict__ o0q, u16* __restrict__ o0k, u16* __restrict__ o0v,
    u16* __restrict__ o1, const float* __restrict__ bias,
    float* __restrict__ o2, const float* __restrict__ resid)
{
  __shared__ alignas(16) u16 As[128 * 32];
  __shared__ alignas(16) u16 Bs[128 * 32];
  const int tid = threadIdx.x, lane = tid & 63, wave = tid >> 6;
  const int wr = wave >> 1, wc = wave & 1;
  const int row0 = blockIdx.y * 128, col0 = blockIdx.x * 128;
  const int fr = lane & 15, g = lane >> 4;

  // staging: wave w, instr i in {0,1}: rows (i*4+w)*16 + lane/4, cols (lane&3)*8
  const int sr0 = wave * 16 + (lane >> 2);
  const int sc  = (lane & 3) * 8;
  const u16* Ap0 = A  + (size_t)(row0 + sr0) * K + sc;
  const u16* Ap1 = A  + (size_t)(row0 + 64 + sr0) * K + sc;
  const u16* Bp0 = BT + (size_t)(col0 + sr0) * K + sc;
  const u16* Bp1 = BT + (size_t)(col0 + 64 + sr0) * K + sc;
  u16* Asl0 = &As[wave * 512];
  u16* Asl1 = &As[(4 + wave) * 512];
  u16* Bsl0 = &Bs[wave * 512];
  u16* Bsl1 = &Bs[(4 + wave) * 512];

  f32x4 acc[4][4] = {};

  for (int k0 = 0; k0 < K; k0 += 32) {
    __syncthreads();
    gload16(Ap0 + k0, Asl0);
    gload16(Ap1 + k0, Asl1);
    gload16(Bp0 + k0, Bsl0);
    gload16(Bp1 + k0, Bsl1);
    __syncthreads();
    s16x8 af[4], bf[4];
    #pragma unroll
    for (int m = 0; m < 4; ++m)
      af[m] = *(const s16x8*)&As[(wr * 64 + m * 16 + fr) * 32 + g * 8];
    #pragma unroll
    for (int n = 0; n < 4; ++n)
      bf[n] = *(const s16x8*)&Bs[(wc * 64 + n * 16 + fr) * 32 + g * 8];
    #pragma unroll
    for (int m = 0; m < 4; ++m)
      #pragma unroll
      for (int n = 0; n < 4; ++n)
        acc[m][n] = __builtin_amdgcn_mfma_f32_16x16x32_bf16(af[m], bf[n], acc[m][n], 0, 0, 0);
  }

  const float QSCALE = 0.03125f * 1.4426950408889634f;  // d^-0.5 * log2(e)
  #pragma unroll
  for (int m = 0; m < 4; ++m) {
    const int rbase = row0 + wr * 64 + m * 16 + g * 4;
    #pragma unroll
    for (int n = 0; n < 4; ++n) {
      const int col = col0 + wc * 64 + n * 16 + fr;
      if constexpr (MODE == 0) {
        const int w = col >> 10, h = (col >> 6) & 15, e = col & 63;
        const int b = rbase >> 11, t0 = rbase & 2047;
        const int bh = b * 16 + h;
        if (w == 0) {
          #pragma unroll
          for (int j = 0; j < 4; ++j)
            o0q[((size_t)bh * 2048 + (t0 + j)) * 64 + e] = f2bf(acc[m][n][j] * QSCALE);
        } else if (w == 1) {
          #pragma unroll
          for (int j = 0; j < 4; ++j)
            o0k[((size_t)bh * 2048 + (t0 + j)) * 64 + e] = f2bf(acc[m][n][j]);
        } else {
          ushort4 pk;
          pk.x = f2bf(acc[m][n][0]); pk.y = f2bf(acc[m][n][1]);
          pk.z = f2bf(acc[m][n][2]); pk.w = f2bf(acc[m][n][3]);
          *(ushort4*)&o0v[((size_t)bh * 64 + e) * 2048 + t0] = pk;   // V^T [bh][e][t]
        }
      } else if constexpr (MODE == 1) {
        const float bb = bias[col];
        #pragma unroll
        for (int j = 0; j < 4; ++j) {
          float v = fmaxf(acc[m][n][j] + bb, 0.0f);
          o1[(size_t)(rbase + j) * 4096 + col] = f2bf(v);
        }
      } else {
        const float bb = bias[col];
        #pragma unroll
        for (int j = 0; j < 4; ++j) {
          const size_t ix = (size_t)(rbase + j) * 1024 + col;
          o2[ix] = acc[m][n][j] + bb + resid[ix];
        }
      }
    }
  }
}

// ---------------------------------------------------------------------------
// MFMA flash attention, NO-MAX softmax (scores bounded; softmax shift-inv).
// q pre-scaled by d^-0.5*log2e so P = exp2(QK^T). Denominator = plain sum ->
// per-lane partials, single reduce at end. No per-chunk cross-lane ops.
// 1 wave = 1 (bh, 16-row q-tile); 4 independent waves/block, no barriers.
// K row-major [bh][t][64]; V transposed [bh][e][t].
// ---------------------------------------------------------------------------
__global__ __launch_bounds__(256) void attn_mfma(
    const u16* __restrict__ q, const u16* __restrict__ krow,
    const u16* __restrict__ vT, const float* __restrict__ embds,
    float* __restrict__ e2)
{
  __shared__ alignas(16) u16 p_sm[4][16][72];   // per-wave P buffer, 144B rows
  const int tid = threadIdx.x, lane = tid & 63, wave = tid >> 6;
  const int task = blockIdx.x * 4 + wave;       // 4096 tasks
  const int bh = task & 31;
  const int qt = 127 - (task >> 5);             // long q-tiles first
  const int q0 = qt * 16;
  const int b = bh >> 4, h = bh & 15;
  const int fr = lane & 15, g = lane >> 4;

  const u16* qp = q + ((size_t)bh * 2048 + q0 + fr) * 64 + g * 8;
  const s16x8 qf0 = *(const s16x8*)(qp);
  const s16x8 qf1 = *(const s16x8*)(qp + 32);

  f32x4 o_acc[4] = {};
  float lacc[4] = {};

  const size_t kvbase = (size_t)bh * 2048 * 64;
  const u16* kp_base = krow + kvbase + (size_t)fr * 64 + g * 8;   // +s*64 per row
  const u16* vp_base = vT + kvbase + (size_t)fr * 2048 + g * 8;   // +e*2048, +s
  const int nch = ((q0 + 15) >> 6) + 1;

  for (int c = 0; c < nch; ++c) {
    const int s0 = c * 64;

    // ---- QK^T: S[16 q][64 s] (units of log2e) ----
    f32x4 sacc[4] = {};
    #pragma unroll
    for (int n = 0; n < 4; ++n) {
      const u16* kp = kp_base + (size_t)(s0 + n * 16) * 64;
      const s16x8 kf0 = *(const s16x8*)(kp);
      const s16x8 kf1 = *(const s16x8*)(kp + 32);
      sacc[n] = __builtin_amdgcn_mfma_f32_16x16x32_bf16(qf0, kf0, sacc[n], 0, 0, 0);
      sacc[n] = __builtin_amdgcn_mfma_f32_16x16x32_bf16(qf1, kf1, sacc[n], 0, 0, 0);
    }

    // ---- causal mask (diagonal chunk only) ----
    if (s0 + 63 > q0) {
      #pragma unroll
      for (int n = 0; n < 4; ++n) {
        const int s = s0 + n * 16 + fr;
        #pragma unroll
        for (int j = 0; j < 4; ++j)
          if (s > q0 + g * 4 + j) sacc[n][j] = -1e30f;
      }
    }

    // ---- P = exp2(S); accumulate denominator per-lane ----
    float p[4][4];
    #pragma unroll
    for (int n = 0; n < 4; ++n)
      #pragma unroll
      for (int j = 0; j < 4; ++j) {
        p[n][j] = __builtin_amdgcn_exp2f(sacc[n][j]);
        lacc[j] += p[n][j];
      }

    // ---- P -> LDS (transpose to A-frag layout); single-wave in-order DS ----
    #pragma unroll
    for (int n = 0; n < 4; ++n)
      #pragma unroll
      for (int j = 0; j < 4; ++j)
        p_sm[wave][g * 4 + j][n * 16 + fr] = f2bf(p[n][j]);

    const s16x8 pf0 = *(const s16x8*)&p_sm[wave][fr][g * 8];
    const s16x8 pf1 = *(const s16x8*)&p_sm[wave][fr][32 + g * 8];

    // ---- PV: O += P[16 q][64 s] * V[64 s][64 e] ----
    #pragma unroll
    for (int n = 0; n < 4; ++n) {
      const u16* vp = vp_base + (size_t)(n * 16) * 2048 + s0;
      const s16x8 vf0 = *(const s16x8*)(vp);
      const s16x8 vf1 = *(const s16x8*)(vp + 32);
      o_acc[n] = __builtin_amdgcn_mfma_f32_16x16x32_bf16(pf0, vf0, o_acc[n], 0, 0, 0);
      o_acc[n] = __builtin_amdgcn_mfma_f32_16x16x32_bf16(pf1, vf1, o_acc[n], 0, 0, 0);
    }
  }

  // ---- final denominator reduce (within 16-lane groups) ----
  #pragma unroll
  for (int j = 0; j < 4; ++j) {
    #pragma unroll
    for (int mm = 1; mm < 16; mm <<= 1) lacc[j] += __shfl_xor(lacc[j], mm);
  }

  // ---- epilogue: e2 = embds + O/l ----
  #pragma unroll
  for (int n = 0; n < 4; ++n) {
    #pragma unroll
    for (int j = 0; j < 4; ++j) {
      const int t = q0 + g * 4 + j;
      const size_t oi = ((size_t)b * 2048 + t) * 1024 + (size_t)h * 64 + n * 16 + fr;
      e2[oi] = embds[oi] + o_acc[n][j] / lacc[j];
    }
  }
}

// ---------------------------------------------------------------------------
extern "C" void kernel_launch(void* const* d_in, const int* in_sizes, int n_in,
                              void* d_out, int out_size, void* d_ws, size_t ws_size,
                              hipStream_t stream) {
  const float* embds = (const float*)d_in[0];
  const float* Wq    = (const float*)d_in[1];
  const float* Wk    = (const float*)d_in[2];
  const float* Wv    = (const float*)d_in[3];
  const float* ln1g  = (const float*)d_in[4];
  const float* ln1b  = (const float*)d_in[5];
  const float* ln2g  = (const float*)d_in[6];
  const float* ln2b  = (const float*)d_in[7];
  const float* W1    = (const float*)d_in[8];
  const float* b1    = (const float*)d_in[9];
  const float* W2    = (const float*)d_in[10];
  const float* b2    = (const float*)d_in[11];
  float* out = (float*)d_out;

  char* ws = (char*)d_ws;
  u16*   xln   = (u16*)(ws);                          // 8 MB  xln [4096][1024] bf16
  u16*   wqkvT = (u16*)(ws + (8ull  << 20));          // 6 MB  [3072][1024]
  u16*   qbuf  = (u16*)(ws + (14ull << 20));          // 8 MB  [bh][t][64]
  u16*   krow  = (u16*)(ws + (22ull << 20));          // 8 MB  [bh][t][64]
  u16*   vTb   = (u16*)(ws + (30ull << 20));          // 8 MB  [bh][e][t]
  float* e2    = (float*)(ws + (38ull << 20));        // 16 MB embds2 f32
  u16*   ybuf  = (u16*)(ws + (54ull << 20));          // 8 MB
  u16*   w1T   = (u16*)(ws + (62ull << 20));          // 8 MB  [4096][1024]
  u16*   w2T   = (u16*)(ws + (70ull << 20));          // 8 MB  [1024][4096]
  u16*   hid   = (u16*)(ws + (78ull << 20));          // 32 MB [4096][4096]

  transpose_pack<<<dim3(1, 16, 16), 256, 0, stream>>>(Wq, wqkvT, 1024, 64);
  transpose_pack<<<dim3(1, 16, 16), 256, 0, stream>>>(Wk, wqkvT + (1u << 20), 1024, 64);
  transpose_pack<<<dim3(1, 16, 16), 256, 0, stream>>>(Wv, wqkvT + (2u << 20), 1024, 64);
  transpose_pack<<<dim3(64, 16, 1), 256, 0, stream>>>(W1, w1T, 1024, 4096);
  transpose_pack<<<dim3(16, 64, 1), 256, 0, stream>>>(W2, w2T, 4096, 1024);
  ln_kernel<<<4096, 256, 0, stream>>>(embds, ln1g, ln1b, xln);
  gemm128<0><<<dim3(24, 32), 256, 0, stream>>>(xln, wqkvT, 1024,
      qbuf, krow, vTb, nullptr, nullptr, nullptr, nullptr);
  attn_mfma<<<1024, 256, 0, stream>>>(qbuf, krow, vTb, embds, e2);
  ln_kernel<<<4096, 256, 0, stream>>>(e2, ln2g, ln2b, ybuf);
  gemm128<1><<<dim3(32, 32), 256, 0, stream>>>(ybuf, w1T, 1024,
      nullptr, nullptr, nullptr, hid, b1, nullptr, nullptr);
  gemm128<2><<<dim3(8, 32), 256, 0, stream>>>(hid, w2T, 4096,
      nullptr, nullptr, nullptr, nullptr, b2, out, e2);
}

// Round 4
// 258.708 us; speedup vs baseline: 25.2319x; 1.3978x over previous
//
#include <hip/hip_runtime.h>

using s16x8 = __attribute__((ext_vector_type(8))) short;
using f32x4 = __attribute__((ext_vector_type(4))) float;
typedef unsigned int   u32;
typedef unsigned short u16;

__device__ __forceinline__ u16 f2bf(float f) {
  u32 u = __float_as_uint(f);
  u += 0x7fffu + ((u >> 16) & 1u);   // round-to-nearest-even
  return (u16)(u >> 16);
}
__device__ __forceinline__ float bf2f(u16 s) {
  return __uint_as_float(((u32)s) << 16);
}

typedef __attribute__((address_space(1))) const unsigned int g_u32;
typedef __attribute__((address_space(3))) unsigned int l_u32;
__device__ __forceinline__ void gload16(const void* g, void* l) {
  __builtin_amdgcn_global_load_lds((g_u32*)g, (l_u32*)l, 16, 0, 0);
}

// K fragment-order address (u16 index): [bh][chunk][pair(n,h)][lane][8]
//   t = token, e = head-dim elem
__device__ __forceinline__ size_t kfrag_addr(int bh, int t, int e) {
  const int pair = (((t >> 4) & 3) << 1) + (e >> 5);
  const int slot = ((e >> 3) & 3) * 16 + (t & 15);
  return ((((size_t)bh * 32 + (t >> 6)) * 8 + pair) * 64 + slot) * 8 + (e & 7);
}
// V fragment-order address: subtile n = e>>4, k-dim = token
__device__ __forceinline__ size_t vfrag_addr(int bh, int t, int e) {
  const int pair = (((e >> 4) & 3) << 1) + ((t >> 5) & 1);
  const int slot = ((t >> 3) & 3) * 16 + (e & 15);
  return ((((size_t)bh * 32 + (t >> 6)) * 8 + pair) * 64 + slot) * 8 + (t & 7);
}

// ---------------------------------------------------------------------------
// Tiled transpose+pack: src f32 [z][R][C] -> dst bf16 [z][C][R]. 64x64 tiles.
// ---------------------------------------------------------------------------
__global__ __launch_bounds__(256) void transpose_pack(
    const float* __restrict__ src, u16* __restrict__ dst, int R, int C)
{
  __shared__ u16 tile[64][66];
  const int tid = threadIdx.x;
  const int c0 = blockIdx.x * 64, r0 = blockIdx.y * 64;
  const size_t zoff = (size_t)blockIdx.z * R * C;
  src += zoff; dst += zoff;
  const int rr = tid >> 6, cc = tid & 63;
  #pragma unroll
  for (int i = 0; i < 16; ++i)
    tile[i * 4 + rr][cc] = f2bf(src[(size_t)(r0 + i * 4 + rr) * C + c0 + cc]);
  __syncthreads();
  #pragma unroll
  for (int i = 0; i < 16; ++i)
    dst[(size_t)(c0 + i * 4 + rr) * R + r0 + cc] = tile[cc][i * 4 + rr];
}

// ---------------------------------------------------------------------------
// LayerNorm: f32 [4096][1024] -> bf16 [4096][1024]. One block per row.
// ---------------------------------------------------------------------------
__global__ __launch_bounds__(256) void ln_kernel(
    const float* __restrict__ x, const float* __restrict__ g,
    const float* __restrict__ be, u16* __restrict__ out)
{
  const int row = blockIdx.x, tid = threadIdx.x;
  const int lane = tid & 63, wave = tid >> 6;
  const float4 v = ((const float4*)(x + (size_t)row * 1024))[tid];
  float s  = v.x + v.y + v.z + v.w;
  float sq = v.x * v.x + v.y * v.y + v.z * v.z + v.w * v.w;
  #pragma unroll
  for (int m = 1; m < 64; m <<= 1) { s += __shfl_xor(s, m); sq += __shfl_xor(sq, m); }
  __shared__ float rs[4], rq[4];
  if (lane == 0) { rs[wave] = s; rq[wave] = sq; }
  __syncthreads();
  s  = rs[0] + rs[1] + rs[2] + rs[3];
  sq = rq[0] + rq[1] + rq[2] + rq[3];
  const float mean = s * (1.0f / 1024.0f);
  const float var  = sq * (1.0f / 1024.0f) - mean * mean;
  const float rstd = rsqrtf(var + 1e-5f);
  const int c = tid * 4;
  const float4 gv = ((const float4*)g)[tid];
  const float4 bv = ((const float4*)be)[tid];
  ushort4 o;
  o.x = f2bf((v.x - mean) * rstd * gv.x + bv.x);
  o.y = f2bf((v.y - mean) * rstd * gv.y + bv.y);
  o.z = f2bf((v.z - mean) * rstd * gv.z + bv.z);
  o.w = f2bf((v.w - mean) * rstd * gv.w + bv.w);
  *(ushort4*)&out[(size_t)row * 1024 + c] = o;
}

// ---------------------------------------------------------------------------
// m97-structure bf16 GEMM: C[M][N] = A[M][K]*BT[N][K]^T. 128x128 tile, BK=32,
// 4 waves (2x2 of 64x64), 4x4 16x16x32 fragments/wave, global_load_lds(16B).
// MODE 0: QKV epilogue (q scaled by LOG2E/32 -> [bh][t][64];
//         K,V -> fragment-order layouts, see kfrag_addr/vfrag_addr)
// MODE 1: +bias, ReLU -> bf16 hid [4096][4096]
// MODE 2: +bias +resid -> f32 out [4096][1024]
// ---------------------------------------------------------------------------
template<int MODE>
__global__ __launch_bounds__(256) void gemm128(
    const u16* __restrict__ A, const u16* __restrict__ BT, int K,
    u16* __restrict__ o0q, u16* __restrict__ o0k, u16* __restrict__ o0v,
    u16* __restrict__ o1, const float* __restrict__ bias,
    float* __restrict__ o2, const float* __restrict__ resid)
{
  __shared__ alignas(16) u16 As[128 * 32];
  __shared__ alignas(16) u16 Bs[128 * 32];
  const int tid = threadIdx.x, lane = tid & 63, wave = tid >> 6;
  const int wr = wave >> 1, wc = wave & 1;
  const int row0 = blockIdx.y * 128, col0 = blockIdx.x * 128;
  const int fr = lane & 15, g = lane >> 4;

  const int sr0 = wave * 16 + (lane >> 2);
  const int sc  = (lane & 3) * 8;
  const u16* Ap0 = A  + (size_t)(row0 + sr0) * K + sc;
  const u16* Ap1 = A  + (size_t)(row0 + 64 + sr0) * K + sc;
  const u16* Bp0 = BT + (size_t)(col0 + sr0) * K + sc;
  const u16* Bp1 = BT + (size_t)(col0 + 64 + sr0) * K + sc;
  u16* Asl0 = &As[wave * 512];
  u16* Asl1 = &As[(4 + wave) * 512];
  u16* Bsl0 = &Bs[wave * 512];
  u16* Bsl1 = &Bs[(4 + wave) * 512];

  f32x4 acc[4][4] = {};

  for (int k0 = 0; k0 < K; k0 += 32) {
    __syncthreads();
    gload16(Ap0 + k0, Asl0);
    gload16(Ap1 + k0, Asl1);
    gload16(Bp0 + k0, Bsl0);
    gload16(Bp1 + k0, Bsl1);
    __syncthreads();
    s16x8 af[4], bf[4];
    #pragma unroll
    for (int m = 0; m < 4; ++m)
      af[m] = *(const s16x8*)&As[(wr * 64 + m * 16 + fr) * 32 + g * 8];
    #pragma unroll
    for (int n = 0; n < 4; ++n)
      bf[n] = *(const s16x8*)&Bs[(wc * 64 + n * 16 + fr) * 32 + g * 8];
    #pragma unroll
    for (int m = 0; m < 4; ++m)
      #pragma unroll
      for (int n = 0; n < 4; ++n)
        acc[m][n] = __builtin_amdgcn_mfma_f32_16x16x32_bf16(af[m], bf[n], acc[m][n], 0, 0, 0);
  }

  const float QSCALE = 0.03125f * 1.4426950408889634f;  // d^-0.5 * log2(e)
  #pragma unroll
  for (int m = 0; m < 4; ++m) {
    const int rbase = row0 + wr * 64 + m * 16 + g * 4;
    #pragma unroll
    for (int n = 0; n < 4; ++n) {
      const int col = col0 + wc * 64 + n * 16 + fr;
      if constexpr (MODE == 0) {
        const int w = col >> 10, h = (col >> 6) & 15, e = col & 63;
        const int b = rbase >> 11, t0 = rbase & 2047;
        const int bh = b * 16 + h;
        if (w == 0) {
          #pragma unroll
          for (int j = 0; j < 4; ++j)
            o0q[((size_t)bh * 2048 + (t0 + j)) * 64 + e] = f2bf(acc[m][n][j] * QSCALE);
        } else if (w == 1) {
          #pragma unroll
          for (int j = 0; j < 4; ++j)
            o0k[kfrag_addr(bh, t0 + j, e)] = f2bf(acc[m][n][j]);
        } else {
          ushort4 pk;
          pk.x = f2bf(acc[m][n][0]); pk.y = f2bf(acc[m][n][1]);
          pk.z = f2bf(acc[m][n][2]); pk.w = f2bf(acc[m][n][3]);
          *(ushort4*)&o0v[vfrag_addr(bh, t0, e)] = pk;   // j -> consecutive elems
        }
      } else if constexpr (MODE == 1) {
        const float bb = bias[col];
        #pragma unroll
        for (int j = 0; j < 4; ++j) {
          float v = fmaxf(acc[m][n][j] + bb, 0.0f);
          o1[(size_t)(rbase + j) * 4096 + col] = f2bf(v);
        }
      } else {
        const float bb = bias[col];
        #pragma unroll
        for (int j = 0; j < 4; ++j) {
          const size_t ix = (size_t)(rbase + j) * 1024 + col;
          o2[ix] = acc[m][n][j] + bb + resid[ix];
        }
      }
    }
  }
}

// ---------------------------------------------------------------------------
// MFMA flash attention, block-cooperative K/V staging.
// Block = (bh, 64-row q-block); 4 waves, each owns 16 q-rows. Per 64-chunk:
// K/V staged to LDS in fragment order via global_load_lds (linear 1024B per
// (wave,instr)), then all waves read conflict-free ds_read_b128 fragments.
// NO-MAX softmax (scores bounded; q pre-scaled by d^-0.5*log2e) ->
// P = exp2(S), denominator = plain sum, one reduce at the end.
// ---------------------------------------------------------------------------
__global__ __launch_bounds__(256) void attn_mfma(
    const u16* __restrict__ q, const u16* __restrict__ kfragG,
    const u16* __restrict__ vfragG, const float* __restrict__ embds,
    float* __restrict__ e2)
{
  __shared__ alignas(16) u16 kbuf[4096];        // [pair][lane][8]
  __shared__ alignas(16) u16 vbuf[4096];
  __shared__ alignas(16) u16 p_sm[4][16][72];   // per-wave P buffer
  const int tid = threadIdx.x, lane = tid & 63, wave = tid >> 6;
  const int bh = blockIdx.x & 31;
  const int qb = 31 - (blockIdx.x >> 5);        // long q-blocks first
  const int q0 = qb * 64 + wave * 16;           // this wave's q-tile base
  const int b = bh >> 4, h = bh & 15;
  const int fr = lane & 15, g = lane >> 4;

  const u16* qp = q + ((size_t)bh * 2048 + q0 + fr) * 64 + g * 8;
  const s16x8 qf0 = *(const s16x8*)(qp);
  const s16x8 qf1 = *(const s16x8*)(qp + 32);

  f32x4 o_acc[4] = {};
  float lacc[4] = {};

  const size_t fragbase = (size_t)bh * 131072;  // 32 chunks * 4096 u16
  const int p0 = wave * 2, p1 = wave * 2 + 1;   // this wave's staging pairs
  const int nch = qb + 1;

  for (int c = 0; c < nch; ++c) {
    const int s0 = c * 64;
    const size_t cb = fragbase + (size_t)c * 4096;

    __syncthreads();                             // prior-chunk reads done
    gload16(kfragG + cb + p0 * 512 + lane * 8, &kbuf[p0 * 512]);
    gload16(kfragG + cb + p1 * 512 + lane * 8, &kbuf[p1 * 512]);
    gload16(vfragG + cb + p0 * 512 + lane * 8, &vbuf[p0 * 512]);
    gload16(vfragG + cb + p1 * 512 + lane * 8, &vbuf[p1 * 512]);
    __syncthreads();                             // staged data visible

    // ---- QK^T: S[16 q][64 s] (units of log2e) ----
    f32x4 sacc[4] = {};
    #pragma unroll
    for (int n = 0; n < 4; ++n) {
      const s16x8 kf0 = *(const s16x8*)&kbuf[(n * 2 + 0) * 512 + lane * 8];
      const s16x8 kf1 = *(const s16x8*)&kbuf[(n * 2 + 1) * 512 + lane * 8];
      sacc[n] = __builtin_amdgcn_mfma_f32_16x16x32_bf16(qf0, kf0, sacc[n], 0, 0, 0);
      sacc[n] = __builtin_amdgcn_mfma_f32_16x16x32_bf16(qf1, kf1, sacc[n], 0, 0, 0);
    }

    // ---- causal mask (diagonal chunk only) ----
    if (s0 + 63 > q0) {
      #pragma unroll
      for (int n = 0; n < 4; ++n) {
        const int s = s0 + n * 16 + fr;
        #pragma unroll
        for (int j = 0; j < 4; ++j)
          if (s > q0 + g * 4 + j) sacc[n][j] = -1e30f;
      }
    }

    // ---- P = exp2(S); accumulate denominator per-lane ----
    float p[4][4];
    #pragma unroll
    for (int n = 0; n < 4; ++n)
      #pragma unroll
      for (int j = 0; j < 4; ++j) {
        p[n][j] = __builtin_amdgcn_exp2f(sacc[n][j]);
        lacc[j] += p[n][j];
      }

    // ---- P -> LDS (transpose to A-frag layout); per-wave, in-order DS ----
    #pragma unroll
    for (int n = 0; n < 4; ++n)
      #pragma unroll
      for (int j = 0; j < 4; ++j)
        p_sm[wave][g * 4 + j][n * 16 + fr] = f2bf(p[n][j]);

    const s16x8 pf0 = *(const s16x8*)&p_sm[wave][fr][g * 8];
    const s16x8 pf1 = *(const s16x8*)&p_sm[wave][fr][32 + g * 8];

    // ---- PV: O += P[16 q][64 s] * V[64 s][64 e] ----
    #pragma unroll
    for (int n = 0; n < 4; ++n) {
      const s16x8 vf0 = *(const s16x8*)&vbuf[(n * 2 + 0) * 512 + lane * 8];
      const s16x8 vf1 = *(const s16x8*)&vbuf[(n * 2 + 1) * 512 + lane * 8];
      o_acc[n] = __builtin_amdgcn_mfma_f32_16x16x32_bf16(pf0, vf0, o_acc[n], 0, 0, 0);
      o_acc[n] = __builtin_amdgcn_mfma_f32_16x16x32_bf16(pf1, vf1, o_acc[n], 0, 0, 0);
    }
  }

  // ---- final denominator reduce (within 16-lane groups) ----
  #pragma unroll
  for (int j = 0; j < 4; ++j) {
    #pragma unroll
    for (int mm = 1; mm < 16; mm <<= 1) lacc[j] += __shfl_xor(lacc[j], mm);
  }

  // ---- epilogue: e2 = embds + O/l ----
  #pragma unroll
  for (int n = 0; n < 4; ++n) {
    #pragma unroll
    for (int j = 0; j < 4; ++j) {
      const int t = q0 + g * 4 + j;
      const size_t oi = ((size_t)b * 2048 + t) * 1024 + (size_t)h * 64 + n * 16 + fr;
      e2[oi] = embds[oi] + o_acc[n][j] / lacc[j];
    }
  }
}

// ---------------------------------------------------------------------------
extern "C" void kernel_launch(void* const* d_in, const int* in_sizes, int n_in,
                              void* d_out, int out_size, void* d_ws, size_t ws_size,
                              hipStream_t stream) {
  const float* embds = (const float*)d_in[0];
  const float* Wq    = (const float*)d_in[1];
  const float* Wk    = (const float*)d_in[2];
  const float* Wv    = (const float*)d_in[3];
  const float* ln1g  = (const float*)d_in[4];
  const float* ln1b  = (const float*)d_in[5];
  const float* ln2g  = (const float*)d_in[6];
  const float* ln2b  = (const float*)d_in[7];
  const float* W1    = (const float*)d_in[8];
  const float* b1    = (const float*)d_in[9];
  const float* W2    = (const float*)d_in[10];
  const float* b2    = (const float*)d_in[11];
  float* out = (float*)d_out;

  char* ws = (char*)d_ws;
  u16*   xln   = (u16*)(ws);                          // 8 MB  xln [4096][1024] bf16
  u16*   wqkvT = (u16*)(ws + (8ull  << 20));          // 6 MB  [3072][1024]
  u16*   qbuf  = (u16*)(ws + (14ull << 20));          // 8 MB  [bh][t][64]
  u16*   kfrag = (u16*)(ws + (22ull << 20));          // 8 MB  frag order
  u16*   vfrag = (u16*)(ws + (30ull << 20));          // 8 MB  frag order
  float* e2    = (float*)(ws + (38ull << 20));        // 16 MB embds2 f32
  u16*   ybuf  = (u16*)(ws + (54ull << 20));          // 8 MB
  u16*   w1T   = (u16*)(ws + (62ull << 20));          // 8 MB  [4096][1024]
  u16*   w2T   = (u16*)(ws + (70ull << 20));          // 8 MB  [1024][4096]
  u16*   hid   = (u16*)(ws + (78ull << 20));          // 32 MB [4096][4096]

  transpose_pack<<<dim3(1, 16, 16), 256, 0, stream>>>(Wq, wqkvT, 1024, 64);
  transpose_pack<<<dim3(1, 16, 16), 256, 0, stream>>>(Wk, wqkvT + (1u << 20), 1024, 64);
  transpose_pack<<<dim3(1, 16, 16), 256, 0, stream>>>(Wv, wqkvT + (2u << 20), 1024, 64);
  transpose_pack<<<dim3(64, 16, 1), 256, 0, stream>>>(W1, w1T, 1024, 4096);
  transpose_pack<<<dim3(16, 64, 1), 256, 0, stream>>>(W2, w2T, 4096, 1024);
  ln_kernel<<<4096, 256, 0, stream>>>(embds, ln1g, ln1b, xln);
  gemm128<0><<<dim3(24, 32), 256, 0, stream>>>(xln, wqkvT, 1024,
      qbuf, kfrag, vfrag, nullptr, nullptr, nullptr, nullptr);
  attn_mfma<<<1024, 256, 0, stream>>>(qbuf, kfrag, vfrag, embds, e2);
  ln_kernel<<<4096, 256, 0, stream>>>(e2, ln2g, ln2b, ybuf);
  gemm128<1><<<dim3(32, 32), 256, 0, stream>>>(ybuf, w1T, 1024,
      nullptr, nullptr, nullptr, hid, b1, nullptr, nullptr);
  gemm128<2><<<dim3(8, 32), 256, 0, stream>>>(hid, w2T, 4096,
      nullptr, nullptr, nullptr, nullptr, b2, out, e2);
}

// Round 5
// 225.010 us; speedup vs baseline: 29.0108x; 1.1498x over previous
//
#include <hip/hip_runtime.h>

using s16x8 = __attribute__((ext_vector_type(8))) short;
using f32x4 = __attribute__((ext_vector_type(4))) float;
typedef unsigned int   u32;
typedef unsigned short u16;

__device__ __forceinline__ u16 f2bf(float f) {
  u32 u = __float_as_uint(f);
  u += 0x7fffu + ((u >> 16) & 1u);   // round-to-nearest-even
  return (u16)(u >> 16);
}
__device__ __forceinline__ float bf2f(u16 s) {
  return __uint_as_float(((u32)s) << 16);
}

typedef __attribute__((address_space(1))) const unsigned int g_u32;
typedef __attribute__((address_space(3))) unsigned int l_u32;
__device__ __forceinline__ void gload16(const void* g, void* l) {
  __builtin_amdgcn_global_load_lds((g_u32*)g, (l_u32*)l, 16, 0, 0);
}

// K fragment-order address (u16 index): [bh][chunk][pair(n,h)][lane][8]
__device__ __forceinline__ size_t kfrag_addr(int bh, int t, int e) {
  const int pair = (((t >> 4) & 3) << 1) + (e >> 5);
  const int slot = ((e >> 3) & 3) * 16 + (t & 15);
  return ((((size_t)bh * 32 + (t >> 6)) * 8 + pair) * 64 + slot) * 8 + (e & 7);
}
// V fragment-order address: subtile n = e>>4, k-dim = token
__device__ __forceinline__ size_t vfrag_addr(int bh, int t, int e) {
  const int pair = (((e >> 4) & 3) << 1) + ((t >> 5) & 1);
  const int slot = ((t >> 3) & 3) * 16 + (e & 15);
  return ((((size_t)bh * 32 + (t >> 6)) * 8 + pair) * 64 + slot) * 8 + (t & 7);
}

// ---------------------------------------------------------------------------
// Tiled transpose+pack: src f32 [z][R][C] -> dst bf16 [z][C][R]. 64x64 tiles.
// ---------------------------------------------------------------------------
__global__ __launch_bounds__(256) void transpose_pack(
    const float* __restrict__ src, u16* __restrict__ dst, int R, int C)
{
  __shared__ u16 tile[64][66];
  const int tid = threadIdx.x;
  const int c0 = blockIdx.x * 64, r0 = blockIdx.y * 64;
  const size_t zoff = (size_t)blockIdx.z * R * C;
  src += zoff; dst += zoff;
  const int rr = tid >> 6, cc = tid & 63;
  #pragma unroll
  for (int i = 0; i < 16; ++i)
    tile[i * 4 + rr][cc] = f2bf(src[(size_t)(r0 + i * 4 + rr) * C + c0 + cc]);
  __syncthreads();
  #pragma unroll
  for (int i = 0; i < 16; ++i)
    dst[(size_t)(c0 + i * 4 + rr) * R + r0 + cc] = tile[cc][i * 4 + rr];
}

// ---------------------------------------------------------------------------
// LayerNorm: f32 [4096][1024] -> bf16 [4096][1024]. One block per row.
// ---------------------------------------------------------------------------
__global__ __launch_bounds__(256) void ln_kernel(
    const float* __restrict__ x, const float* __restrict__ g,
    const float* __restrict__ be, u16* __restrict__ out)
{
  const int row = blockIdx.x, tid = threadIdx.x;
  const int lane = tid & 63, wave = tid >> 6;
  const float4 v = ((const float4*)(x + (size_t)row * 1024))[tid];
  float s  = v.x + v.y + v.z + v.w;
  float sq = v.x * v.x + v.y * v.y + v.z * v.z + v.w * v.w;
  #pragma unroll
  for (int m = 1; m < 64; m <<= 1) { s += __shfl_xor(s, m); sq += __shfl_xor(sq, m); }
  __shared__ float rs[4], rq[4];
  if (lane == 0) { rs[wave] = s; rq[wave] = sq; }
  __syncthreads();
  s  = rs[0] + rs[1] + rs[2] + rs[3];
  sq = rq[0] + rq[1] + rq[2] + rq[3];
  const float mean = s * (1.0f / 1024.0f);
  const float var  = sq * (1.0f / 1024.0f) - mean * mean;
  const float rstd = rsqrtf(var + 1e-5f);
  const int c = tid * 4;
  const float4 gv = ((const float4*)g)[tid];
  const float4 bv = ((const float4*)be)[tid];
  ushort4 o;
  o.x = f2bf((v.x - mean) * rstd * gv.x + bv.x);
  o.y = f2bf((v.y - mean) * rstd * gv.y + bv.y);
  o.z = f2bf((v.z - mean) * rstd * gv.z + bv.z);
  o.w = f2bf((v.w - mean) * rstd * gv.w + bv.w);
  *(ushort4*)&out[(size_t)row * 1024 + c] = o;
}

// ---------------------------------------------------------------------------
// bf16 MFMA GEMM: C = A[M][K]*BT[N][K]^T. Tile (64*MR)x128, BK=32, 4 waves,
// double-buffered LDS, single barrier per K-step, swizzled staging (2-way
// bank spread), XCD-aware block swizzle.
// MODE 0: QKV epilogue  MODE 1: +bias+ReLU->bf16  MODE 2: +bias+resid->f32
// ---------------------------------------------------------------------------
template<int MODE, int MR>
__global__ __launch_bounds__(256) void gemm128(
    const u16* __restrict__ A, const u16* __restrict__ BT, int K,
    u16* __restrict__ o0q, u16* __restrict__ o0k, u16* __restrict__ o0v,
    u16* __restrict__ o1, const float* __restrict__ bias,
    float* __restrict__ o2, const float* __restrict__ resid)
{
  constexpr int BM = 64 * MR;
  __shared__ alignas(16) u16 As[2][BM * 32];
  __shared__ alignas(16) u16 Bs[2][128 * 32];
  const int tid = threadIdx.x, lane = tid & 63, wave = tid >> 6;
  const int wr = wave >> 1, wc = wave & 1;
  // XCD-aware swizzle (all grids have nwg % 8 == 0)
  const int gx = gridDim.x;
  const int nwg = gx * gridDim.y;
  int lid = blockIdx.y * gx + blockIdx.x;
  lid = (lid & 7) * (nwg >> 3) + (lid >> 3);
  const int row0 = (lid / gx) * BM, col0 = (lid % gx) * 128;
  const int fr = lane & 15, g = lane >> 4;
  const int swz = (g ^ ((fr >> 1) & 3)) * 8;           // read-side slot swizzle

  const int sr = wave * 16 + (lane >> 2);
  const int sc = ((lane & 3) ^ ((lane >> 3) & 3)) * 8; // pre-swizzled source col
  const u16* Ap0 = A  + (size_t)(row0 + sr) * K + sc;
  const u16* Ap1 = A  + (size_t)(row0 + 64 + sr) * K + sc;   // MR==2 only
  const u16* Bp0 = BT + (size_t)(col0 + sr) * K + sc;
  const u16* Bp1 = BT + (size_t)(col0 + 64 + sr) * K + sc;

  f32x4 acc[2 * MR][4] = {};

  auto stage = [&](int sel, int k0) {
    gload16(Ap0 + k0, &As[sel][wave * 512]);
    if constexpr (MR == 2) gload16(Ap1 + k0, &As[sel][(4 + wave) * 512]);
    gload16(Bp0 + k0, &Bs[sel][wave * 512]);
    gload16(Bp1 + k0, &Bs[sel][(4 + wave) * 512]);
  };

  stage(0, 0);
  __syncthreads();
  int cur = 0;
  for (int k0 = 0; k0 < K; k0 += 32) {
    if (k0 + 32 < K) stage(cur ^ 1, k0 + 32);        // prefetch next tile
    s16x8 af[2 * MR], bfr[4];
    #pragma unroll
    for (int m = 0; m < 2 * MR; ++m)
      af[m] = *(const s16x8*)&As[cur][(wr * (32 * MR) + m * 16 + fr) * 32 + swz];
    #pragma unroll
    for (int n = 0; n < 4; ++n)
      bfr[n] = *(const s16x8*)&Bs[cur][(wc * 64 + n * 16 + fr) * 32 + swz];
    #pragma unroll
    for (int m = 0; m < 2 * MR; ++m)
      #pragma unroll
      for (int n = 0; n < 4; ++n)
        acc[m][n] = __builtin_amdgcn_mfma_f32_16x16x32_bf16(af[m], bfr[n], acc[m][n], 0, 0, 0);
    __syncthreads();                                  // reads done + prefetch landed
    cur ^= 1;
  }

  const float QSCALE = 0.03125f * 1.4426950408889634f;  // d^-0.5 * log2(e)
  #pragma unroll
  for (int m = 0; m < 2 * MR; ++m) {
    const int rbase = row0 + wr * (32 * MR) + m * 16 + g * 4;
    #pragma unroll
    for (int n = 0; n < 4; ++n) {
      const int col = col0 + wc * 64 + n * 16 + fr;
      if constexpr (MODE == 0) {
        const int w = col >> 10, h = (col >> 6) & 15, e = col & 63;
        const int b = rbase >> 11, t0 = rbase & 2047;
        const int bh = b * 16 + h;
        if (w == 0) {
          #pragma unroll
          for (int j = 0; j < 4; ++j)
            o0q[((size_t)bh * 2048 + (t0 + j)) * 64 + e] = f2bf(acc[m][n][j] * QSCALE);
        } else if (w == 1) {
          #pragma unroll
          for (int j = 0; j < 4; ++j)
            o0k[kfrag_addr(bh, t0 + j, e)] = f2bf(acc[m][n][j]);
        } else {
          ushort4 pk;
          pk.x = f2bf(acc[m][n][0]); pk.y = f2bf(acc[m][n][1]);
          pk.z = f2bf(acc[m][n][2]); pk.w = f2bf(acc[m][n][3]);
          *(ushort4*)&o0v[vfrag_addr(bh, t0, e)] = pk;
        }
      } else if constexpr (MODE == 1) {
        const float bb = bias[col];
        #pragma unroll
        for (int j = 0; j < 4; ++j) {
          float v = fmaxf(acc[m][n][j] + bb, 0.0f);
          o1[(size_t)(rbase + j) * 4096 + col] = f2bf(v);
        }
      } else {
        const float bb = bias[col];
        #pragma unroll
        for (int j = 0; j < 4; ++j) {
          const size_t ix = (size_t)(rbase + j) * 1024 + col;
          o2[ix] = acc[m][n][j] + bb + resid[ix];
        }
      }
    }
  }
}

// ---------------------------------------------------------------------------
// MFMA flash attention, block-cooperative K/V staging, double-buffered.
// Block = (bh, 64-row q-block); 4 waves, each owns 16 q-rows. K/V staged in
// fragment order via global_load_lds; single barrier per chunk; prefetch of
// chunk c+1 overlaps compute of chunk c. NO-MAX softmax (q pre-scaled by
// d^-0.5*log2e): P = exp2(S), denominator = plain sum.
// ---------------------------------------------------------------------------
__global__ __launch_bounds__(256) void attn_mfma(
    const u16* __restrict__ q, const u16* __restrict__ kfragG,
    const u16* __restrict__ vfragG, const float* __restrict__ embds,
    float* __restrict__ e2)
{
  __shared__ alignas(16) u16 kbuf[2][4096];
  __shared__ alignas(16) u16 vbuf[2][4096];
  __shared__ alignas(16) u16 p_sm[4][16][72];
  const int tid = threadIdx.x, lane = tid & 63, wave = tid >> 6;
  const int bh = blockIdx.x & 31;
  const int qb = 31 - (blockIdx.x >> 5);        // long q-blocks first
  const int q0 = qb * 64 + wave * 16;
  const int b = bh >> 4, h = bh & 15;
  const int fr = lane & 15, g = lane >> 4;

  const u16* qp = q + ((size_t)bh * 2048 + q0 + fr) * 64 + g * 8;
  const s16x8 qf0 = *(const s16x8*)(qp);
  const s16x8 qf1 = *(const s16x8*)(qp + 32);

  f32x4 o_acc[4] = {};
  float lacc[4] = {};

  const size_t fragbase = (size_t)bh * 131072;
  const int p0 = wave * 2, p1 = wave * 2 + 1;
  const int nch = qb + 1;

  auto stage_kv = [&](int sel, int c) {
    const size_t cb = fragbase + (size_t)c * 4096;
    gload16(kfragG + cb + p0 * 512 + lane * 8, &kbuf[sel][p0 * 512]);
    gload16(kfragG + cb + p1 * 512 + lane * 8, &kbuf[sel][p1 * 512]);
    gload16(vfragG + cb + p0 * 512 + lane * 8, &vbuf[sel][p0 * 512]);
    gload16(vfragG + cb + p1 * 512 + lane * 8, &vbuf[sel][p1 * 512]);
  };

  stage_kv(0, 0);
  __syncthreads();
  int cur = 0;

  for (int c = 0; c < nch; ++c) {
    if (c + 1 < nch) stage_kv(cur ^ 1, c + 1);   // prefetch next chunk
    const int s0 = c * 64;

    // ---- QK^T: S[16 q][64 s] (units of log2e) ----
    f32x4 sacc[4] = {};
    #pragma unroll
    for (int n = 0; n < 4; ++n) {
      const s16x8 kf0 = *(const s16x8*)&kbuf[cur][(n * 2 + 0) * 512 + lane * 8];
      const s16x8 kf1 = *(const s16x8*)&kbuf[cur][(n * 2 + 1) * 512 + lane * 8];
      sacc[n] = __builtin_amdgcn_mfma_f32_16x16x32_bf16(qf0, kf0, sacc[n], 0, 0, 0);
      sacc[n] = __builtin_amdgcn_mfma_f32_16x16x32_bf16(qf1, kf1, sacc[n], 0, 0, 0);
    }

    // ---- causal mask (diagonal chunk only) ----
    if (s0 + 63 > q0) {
      #pragma unroll
      for (int n = 0; n < 4; ++n) {
        const int s = s0 + n * 16 + fr;
        #pragma unroll
        for (int j = 0; j < 4; ++j)
          if (s > q0 + g * 4 + j) sacc[n][j] = -1e30f;
      }
    }

    // ---- P = exp2(S); denominator per-lane ----
    float p[4][4];
    #pragma unroll
    for (int n = 0; n < 4; ++n)
      #pragma unroll
      for (int j = 0; j < 4; ++j) {
        p[n][j] = __builtin_amdgcn_exp2f(sacc[n][j]);
        lacc[j] += p[n][j];
      }

    // ---- P -> LDS transpose (per-wave, in-order DS) ----
    #pragma unroll
    for (int n = 0; n < 4; ++n)
      #pragma unroll
      for (int j = 0; j < 4; ++j)
        p_sm[wave][g * 4 + j][n * 16 + fr] = f2bf(p[n][j]);

    const s16x8 pf0 = *(const s16x8*)&p_sm[wave][fr][g * 8];
    const s16x8 pf1 = *(const s16x8*)&p_sm[wave][fr][32 + g * 8];

    // ---- PV: O += P * V ----
    #pragma unroll
    for (int n = 0; n < 4; ++n) {
      const s16x8 vf0 = *(const s16x8*)&vbuf[cur][(n * 2 + 0) * 512 + lane * 8];
      const s16x8 vf1 = *(const s16x8*)&vbuf[cur][(n * 2 + 1) * 512 + lane * 8];
      o_acc[n] = __builtin_amdgcn_mfma_f32_16x16x32_bf16(pf0, vf0, o_acc[n], 0, 0, 0);
      o_acc[n] = __builtin_amdgcn_mfma_f32_16x16x32_bf16(pf1, vf1, o_acc[n], 0, 0, 0);
    }

    __syncthreads();                              // reads done + prefetch landed
    cur ^= 1;
  }

  // ---- final denominator reduce (within 16-lane groups) ----
  #pragma unroll
  for (int j = 0; j < 4; ++j) {
    #pragma unroll
    for (int mm = 1; mm < 16; mm <<= 1) lacc[j] += __shfl_xor(lacc[j], mm);
  }

  // ---- epilogue: e2 = embds + O/l ----
  #pragma unroll
  for (int n = 0; n < 4; ++n) {
    #pragma unroll
    for (int j = 0; j < 4; ++j) {
      const int t = q0 + g * 4 + j;
      const size_t oi = ((size_t)b * 2048 + t) * 1024 + (size_t)h * 64 + n * 16 + fr;
      e2[oi] = embds[oi] + o_acc[n][j] / lacc[j];
    }
  }
}

// ---------------------------------------------------------------------------
extern "C" void kernel_launch(void* const* d_in, const int* in_sizes, int n_in,
                              void* d_out, int out_size, void* d_ws, size_t ws_size,
                              hipStream_t stream) {
  const float* embds = (const float*)d_in[0];
  const float* Wq    = (const float*)d_in[1];
  const float* Wk    = (const float*)d_in[2];
  const float* Wv    = (const float*)d_in[3];
  const float* ln1g  = (const float*)d_in[4];
  const float* ln1b  = (const float*)d_in[5];
  const float* ln2g  = (const float*)d_in[6];
  const float* ln2b  = (const float*)d_in[7];
  const float* W1    = (const float*)d_in[8];
  const float* b1    = (const float*)d_in[9];
  const float* W2    = (const float*)d_in[10];
  const float* b2    = (const float*)d_in[11];
  float* out = (float*)d_out;

  char* ws = (char*)d_ws;
  u16*   xln   = (u16*)(ws);                          // 8 MB  xln [4096][1024] bf16
  u16*   wqkvT = (u16*)(ws + (8ull  << 20));          // 6 MB  [3072][1024]
  u16*   qbuf  = (u16*)(ws + (14ull << 20));          // 8 MB  [bh][t][64]
  u16*   kfrag = (u16*)(ws + (22ull << 20));          // 8 MB  frag order
  u16*   vfrag = (u16*)(ws + (30ull << 20));          // 8 MB  frag order
  float* e2    = (float*)(ws + (38ull << 20));        // 16 MB embds2 f32
  u16*   ybuf  = (u16*)(ws + (54ull << 20));          // 8 MB
  u16*   w1T   = (u16*)(ws + (62ull << 20));          // 8 MB  [4096][1024]
  u16*   w2T   = (u16*)(ws + (70ull << 20));          // 8 MB  [1024][4096]
  u16*   hid   = (u16*)(ws + (78ull << 20));          // 32 MB [4096][4096]

  transpose_pack<<<dim3(1, 16, 16), 256, 0, stream>>>(Wq, wqkvT, 1024, 64);
  transpose_pack<<<dim3(1, 16, 16), 256, 0, stream>>>(Wk, wqkvT + (1u << 20), 1024, 64);
  transpose_pack<<<dim3(1, 16, 16), 256, 0, stream>>>(Wv, wqkvT + (2u << 20), 1024, 64);
  transpose_pack<<<dim3(64, 16, 1), 256, 0, stream>>>(W1, w1T, 1024, 4096);
  transpose_pack<<<dim3(16, 64, 1), 256, 0, stream>>>(W2, w2T, 4096, 1024);
  ln_kernel<<<4096, 256, 0, stream>>>(embds, ln1g, ln1b, xln);
  gemm128<0, 2><<<dim3(24, 32), 256, 0, stream>>>(xln, wqkvT, 1024,
      qbuf, kfrag, vfrag, nullptr, nullptr, nullptr, nullptr);
  attn_mfma<<<1024, 256, 0, stream>>>(qbuf, kfrag, vfrag, embds, e2);
  ln_kernel<<<4096, 256, 0, stream>>>(e2, ln2g, ln2b, ybuf);
  gemm128<1, 2><<<dim3(32, 32), 256, 0, stream>>>(ybuf, w1T, 1024,
      nullptr, nullptr, nullptr, hid, b1, nullptr, nullptr);
  gemm128<2, 1><<<dim3(8, 64), 256, 0, stream>>>(hid, w2T, 4096,
      nullptr, nullptr, nullptr, nullptr, b2, out, e2);
}